// Round 2
// baseline (513.538 us; speedup 1.0000x reference)
//
#include <hip/hip_runtime.h>
#include <math.h>

// ---------------------------------------------------------------------------
// PolicyNet scoring, fp32 fused (round 2: capture-safe, <64KB static LDS,
// minimal workspace footprint; raw scores staged in d_out, normalized
// in-place).
//   rel = emb[action_ids]                       [A,128] gather
//   att = softmax_l(Q @ rel)                    [A,64]
//   question = att @ Q                          [A,128]
//   hidden = relu(h1 + question @ W1q^T)        h1 = b1 + W1[:, :128] @ hist
//   out = hidden @ W2^T + b2
//   scores = sum(rel*out, -1); softmax over A
// ---------------------------------------------------------------------------

#define BA     32          // actions per block tile
#define NTHR   256

// LDS float offsets. Static __shared__ of 14848 floats = 59392 B (< 64 KiB,
// 2 blocks/CU of 160 KiB). Aliasing plan:
//   P0-P1: Q[64][132] | REL[32][132] | ATT[32][68]
//   P3:    QUEST written over Q rows 0..31 AFTER a sync (Q dead afterwards)
//   P4:    W1 chunks over Q rows 32..63; HID written over QUEST after the
//          final chunk sync (QUEST reads complete)
//   P5:    W2 chunks over same W region; REL still live; ATT reused as stash
#define OQ     0           // Q      [64][132] = 8448
#define OREL   8448        // REL    [32][132] = 4224
#define OATT   12672       // ATT/w  [32][68]  = 2176
#define OQST   0           // QUEST  [32][132] aliases Q rows 0..31
#define OHID   0           // HID    aliases QUEST
#define OW     4224        // W chunk[32][132] aliases Q rows 32..63
#define LDS_FLOATS 14848

__device__ __forceinline__ float dot4(const float4 a, const float4 b) {
    return fmaf(a.x, b.x, fmaf(a.y, b.y, fmaf(a.z, b.z, a.w * b.w)));
}
__device__ __forceinline__ void fma4(float4& a, float s, const float4 b) {
    a.x = fmaf(s, b.x, a.x); a.y = fmaf(s, b.y, a.y);
    a.z = fmaf(s, b.z, a.z); a.w = fmaf(s, b.w, a.w);
}
__device__ __forceinline__ void add4(float4& a, const float4 b) {
    a.x += b.x; a.y += b.y; a.z += b.z; a.w += b.w;
}
__device__ __forceinline__ void relu4(float4& a) {
    a.x = fmaxf(a.x, 0.f); a.y = fmaxf(a.y, 0.f);
    a.z = fmaxf(a.z, 0.f); a.w = fmaxf(a.w, 0.f);
}

// h1[j] = b1[j] + sum_{k<128} W1[j][k] * hist[k].  One block, 4 waves,
// wave-per-row coalesced reads + 64-lane shuffle reduce.
__global__ void k_prep(const float* __restrict__ hist, const float* __restrict__ W1,
                       const float* __restrict__ b1, float* __restrict__ h1)
{
    const int lane = threadIdx.x & 63;
    const int w    = threadIdx.x >> 6;
    const float h0  = hist[lane];
    const float h64 = hist[64 + lane];
    #pragma unroll 4
    for (int r = 0; r < 32; ++r) {
        const int j = w * 32 + r;
        float p = fmaf(W1[j * 256 + lane], h0, W1[j * 256 + 64 + lane] * h64);
        #pragma unroll
        for (int o = 1; o < 64; o <<= 1) p += __shfl_xor(p, o);
        if (lane == 0) h1[j] = b1[j] + p;
    }
}

__global__ void __launch_bounds__(NTHR, 2)
k_main(const int* __restrict__ action_ids,
       const float* __restrict__ emb,
       const float* __restrict__ Qg,
       const float* __restrict__ W1,
       const float* __restrict__ W2,
       const float* __restrict__ b2,
       const float* __restrict__ h1g,
       float* __restrict__ scores,
       float* __restrict__ mb,
       float* __restrict__ sb,
       int A)
{
    __shared__ __align__(16) float ls[LDS_FLOATS];
    const int tid = threadIdx.x;
    const int a0  = blockIdx.x * BA;

    // ---- P0: stage Q [64][128] -> LDS (stride 132), gather REL rows ----
    {
        const float4* Qg4 = (const float4*)Qg;
        #pragma unroll
        for (int i = tid; i < (64 * 128) / 4; i += NTHR) {   // 8 iters
            const int row = i >> 5, c4 = i & 31;
            *(float4*)&ls[OQ + row * 132 + c4 * 4] = Qg4[i];
        }
        const int a   = tid >> 3;                            // 0..31
        const int seg = tid & 7;                             // 8 thr / row
        const int ga  = a0 + a;
        const int rid = (ga < A) ? action_ids[ga] : 0;
        const float4* er = (const float4*)(emb + (size_t)rid * 128);
        #pragma unroll
        for (int v = 0; v < 4; ++v) {
            const int c4 = v * 8 + seg;
            *(float4*)&ls[OREL + a * 132 + c4 * 4] = er[c4];
        }
    }
    __syncthreads();

    // ---- P1: ATT[32a][64l] = REL @ Q^T (k = 128) ----
    {
        const int ta = tid >> 4;          // action pair {2ta, 2ta+1}
        const int tl = tid & 15;          // l set {tl, tl+16, tl+32, tl+48}
        float acc[2][4] = {};
        #pragma unroll 4
        for (int k4 = 0; k4 < 32; ++k4) {
            const float4 r0 = *(const float4*)&ls[OREL + (2 * ta) * 132 + k4 * 4];
            const float4 r1 = *(const float4*)&ls[OREL + (2 * ta + 1) * 132 + k4 * 4];
            #pragma unroll
            for (int i = 0; i < 4; ++i) {
                const float4 q = *(const float4*)&ls[OQ + (tl + 16 * i) * 132 + k4 * 4];
                acc[0][i] += dot4(r0, q);
                acc[1][i] += dot4(r1, q);
            }
        }
        #pragma unroll
        for (int j = 0; j < 2; ++j)
            #pragma unroll
            for (int i = 0; i < 4; ++i)
                ls[OATT + (2 * ta + j) * 68 + tl + 16 * i] = acc[j][i];
    }
    __syncthreads();

    // ---- P2: softmax over l per action (8 lanes / action) ----
    {
        const int a = tid >> 3;
        const int s = tid & 7;
        float v[8];
        float m = -INFINITY;
        #pragma unroll
        for (int i = 0; i < 8; ++i) {
            v[i] = ls[OATT + a * 68 + s + 8 * i];
            m = fmaxf(m, v[i]);
        }
        m = fmaxf(m, __shfl_xor(m, 1));
        m = fmaxf(m, __shfl_xor(m, 2));
        m = fmaxf(m, __shfl_xor(m, 4));
        float sum = 0.f;
        #pragma unroll
        for (int i = 0; i < 8; ++i) { v[i] = __expf(v[i] - m); sum += v[i]; }
        sum += __shfl_xor(sum, 1);
        sum += __shfl_xor(sum, 2);
        sum += __shfl_xor(sum, 4);
        const float inv = 1.f / sum;
        #pragma unroll
        for (int i = 0; i < 8; ++i)
            ls[OATT + a * 68 + s + 8 * i] = v[i] * inv;
    }
    __syncthreads();

    // ---- P3: QUEST[32a][128d] = w @ Q  (QUEST aliases Q rows 0..31) ----
    {
        const int ta = tid >> 4;
        const int td = tid & 15;          // d f4 set {td, td+16}
        float4 a00 = {0,0,0,0}, a01 = {0,0,0,0}, a10 = {0,0,0,0}, a11 = {0,0,0,0};
        #pragma unroll 4
        for (int l = 0; l < 64; ++l) {
            const float  w0 = ls[OATT + (2 * ta) * 68 + l];
            const float  w1 = ls[OATT + (2 * ta + 1) * 68 + l];
            const float4 q0 = *(const float4*)&ls[OQ + l * 132 + td * 4];
            const float4 q1 = *(const float4*)&ls[OQ + l * 132 + 64 + td * 4];
            fma4(a00, w0, q0); fma4(a01, w0, q1);
            fma4(a10, w1, q0); fma4(a11, w1, q1);
        }
        __syncthreads();   // all Q reads done before QUEST overwrites Q rows 0..31
        *(float4*)&ls[OQST + (2 * ta) * 132 + td * 4]          = a00;
        *(float4*)&ls[OQST + (2 * ta) * 132 + 64 + td * 4]     = a01;
        *(float4*)&ls[OQST + (2 * ta + 1) * 132 + td * 4]      = a10;
        *(float4*)&ls[OQST + (2 * ta + 1) * 132 + 64 + td * 4] = a11;
    }
    __syncthreads();

    // ---- P4: HID = relu(h1 + QUEST @ W1q^T), W1q staged in 4 chunks of 32k
    //          (W chunk aliases Q rows 32..63; HID aliases QUEST at the end) --
    {
        const int ta = tid >> 4;
        const int tj = tid & 15;
        const int jrow = tid >> 1;        // staging: row (output dim j) of W1
        const int half = tid & 1;
        float4 a00 = {0,0,0,0}, a01 = {0,0,0,0}, a10 = {0,0,0,0}, a11 = {0,0,0,0};
        for (int c = 0; c < 4; ++c) {
            // W1c[k][j] = W1[j][128 + c*32 + k]
            #pragma unroll
            for (int v = 0; v < 4; ++v) {
                const float4 t4 = *(const float4*)&W1[jrow * 256 + 128 + c * 32 + half * 16 + v * 4];
                const int kb = half * 16 + v * 4;
                ls[OW + (kb + 0) * 132 + jrow] = t4.x;
                ls[OW + (kb + 1) * 132 + jrow] = t4.y;
                ls[OW + (kb + 2) * 132 + jrow] = t4.z;
                ls[OW + (kb + 3) * 132 + jrow] = t4.w;
            }
            __syncthreads();
            #pragma unroll 4
            for (int k = 0; k < 32; ++k) {
                const float  qA = ls[OQST + (2 * ta) * 132 + c * 32 + k];
                const float  qB = ls[OQST + (2 * ta + 1) * 132 + c * 32 + k];
                const float4 w0 = *(const float4*)&ls[OW + k * 132 + tj * 4];
                const float4 w1 = *(const float4*)&ls[OW + k * 132 + 64 + tj * 4];
                fma4(a00, qA, w0); fma4(a01, qA, w1);
                fma4(a10, qB, w0); fma4(a11, qB, w1);
            }
            __syncthreads();   // protects next chunk's OW overwrite; after c=3,
                               // guarantees all QUEST reads done before HID write
        }
        const float4 g0 = *(const float4*)&h1g[tj * 4];
        const float4 g1 = *(const float4*)&h1g[64 + tj * 4];
        add4(a00, g0); add4(a01, g1); add4(a10, g0); add4(a11, g1);
        relu4(a00); relu4(a01); relu4(a10); relu4(a11);
        *(float4*)&ls[OHID + (2 * ta) * 132 + tj * 4]          = a00;
        *(float4*)&ls[OHID + (2 * ta) * 132 + 64 + tj * 4]     = a01;
        *(float4*)&ls[OHID + (2 * ta + 1) * 132 + tj * 4]      = a10;
        *(float4*)&ls[OHID + (2 * ta + 1) * 132 + 64 + tj * 4] = a11;
    }
    __syncthreads();

    // ---- P5: OUT = HID @ W2^T + b2 ; score = sum(REL*OUT) ----
    {
        const int ta = tid >> 4;
        const int td = tid & 15;
        const int drow = tid >> 1;        // staging: row (output dim d) of W2
        const int half = tid & 1;
        float4 o00 = {0,0,0,0}, o01 = {0,0,0,0}, o10 = {0,0,0,0}, o11 = {0,0,0,0};
        for (int c = 0; c < 4; ++c) {
            // W2c[j][d] = W2[d][c*32 + j]
            #pragma unroll
            for (int v = 0; v < 4; ++v) {
                const float4 t4 = *(const float4*)&W2[drow * 128 + c * 32 + half * 16 + v * 4];
                const int jb = half * 16 + v * 4;
                ls[OW + (jb + 0) * 132 + drow] = t4.x;
                ls[OW + (jb + 1) * 132 + drow] = t4.y;
                ls[OW + (jb + 2) * 132 + drow] = t4.z;
                ls[OW + (jb + 3) * 132 + drow] = t4.w;
            }
            __syncthreads();
            #pragma unroll 4
            for (int j = 0; j < 32; ++j) {
                const float  hA = ls[OHID + (2 * ta) * 132 + c * 32 + j];
                const float  hB = ls[OHID + (2 * ta + 1) * 132 + c * 32 + j];
                const float4 w0 = *(const float4*)&ls[OW + j * 132 + td * 4];
                const float4 w1 = *(const float4*)&ls[OW + j * 132 + 64 + td * 4];
                fma4(o00, hA, w0); fma4(o01, hA, w1);
                fma4(o10, hB, w0); fma4(o11, hB, w1);
            }
            __syncthreads();
        }
        const float4 bb0 = *(const float4*)&b2[td * 4];
        const float4 bb1 = *(const float4*)&b2[64 + td * 4];
        add4(o00, bb0); add4(o01, bb1); add4(o10, bb0); add4(o11, bb1);
        const float4 rA0 = *(const float4*)&ls[OREL + (2 * ta) * 132 + td * 4];
        const float4 rA1 = *(const float4*)&ls[OREL + (2 * ta) * 132 + 64 + td * 4];
        const float4 rB0 = *(const float4*)&ls[OREL + (2 * ta + 1) * 132 + td * 4];
        const float4 rB1 = *(const float4*)&ls[OREL + (2 * ta + 1) * 132 + 64 + td * 4];
        float p0 = dot4(o00, rA0) + dot4(o01, rA1);
        float p1 = dot4(o10, rB0) + dot4(o11, rB1);
        #pragma unroll
        for (int o = 1; o < 16; o <<= 1) {
            p0 += __shfl_xor(p0, o);
            p1 += __shfl_xor(p1, o);
        }
        if (td == 0) {
            const int aA = a0 + 2 * ta, aB = aA + 1;
            if (aA < A) scores[aA] = p0;
            if (aB < A) scores[aB] = p1;
            ls[OATT + 2 * ta]     = p0;   // ATT region dead; stash for reduce
            ls[OATT + 2 * ta + 1] = p1;
        }
    }
    __syncthreads();

    // ---- per-block softmax partials (m_b, s_b) over the 32 tile scores ----
    if (tid < 32) {
        const bool valid = (a0 + tid) < A;
        float sv = valid ? ls[OATT + tid] : -INFINITY;
        float m = sv;
        #pragma unroll
        for (int o = 1; o < 32; o <<= 1) m = fmaxf(m, __shfl_xor(m, o));
        float ex = valid ? __expf(sv - m) : 0.f;
        #pragma unroll
        for (int o = 1; o < 32; o <<= 1) ex += __shfl_xor(ex, o);
        if (tid == 0) { mb[blockIdx.x] = m; sb[blockIdx.x] = ex; }
    }
}

// Combine per-block (m, s) partials into global M and 1/S.
__global__ void k_combine(const float* __restrict__ mb, const float* __restrict__ sb,
                          int n, float* __restrict__ MS)
{
    __shared__ float red[256];
    const int tid = threadIdx.x;
    float m = -INFINITY;
    for (int i = tid; i < n; i += 256) m = fmaxf(m, mb[i]);
    red[tid] = m; __syncthreads();
    for (int s = 128; s > 0; s >>= 1) {
        if (tid < s) red[tid] = fmaxf(red[tid], red[tid + s]);
        __syncthreads();
    }
    const float M = red[0];
    __syncthreads();
    float sum = 0.f;
    for (int i = tid; i < n; i += 256) sum += sb[i] * __expf(mb[i] - M);
    red[tid] = sum; __syncthreads();
    for (int s = 128; s > 0; s >>= 1) {
        if (tid < s) red[tid] += red[tid + s];
        __syncthreads();
    }
    if (tid == 0) { MS[0] = M; MS[1] = 1.f / red[0]; }
}

// In-place: d_out holds raw scores; replace with softmax.
__global__ void k_norm(const float* __restrict__ scores, const float* __restrict__ MS,
                       float* __restrict__ out, int A)
{
    const int i = blockIdx.x * blockDim.x + threadIdx.x;
    if (i < A) out[i] = __expf(scores[i] - MS[0]) * MS[1];
}

extern "C" void kernel_launch(void* const* d_in, const int* in_sizes, int n_in,
                              void* d_out, int out_size, void* d_ws, size_t ws_size,
                              hipStream_t stream)
{
    const int*   action_ids = (const int*)  d_in[0];
    const float* emb        = (const float*)d_in[1];
    const float* Qg         = (const float*)d_in[2];
    const float* hist       = (const float*)d_in[3];
    const float* W1         = (const float*)d_in[4];
    const float* b1         = (const float*)d_in[5];
    const float* W2         = (const float*)d_in[6];
    const float* b2         = (const float*)d_in[7];
    float* out = (float*)d_out;
    const int A    = in_sizes[0];
    const int nblk = (A + BA - 1) / BA;

    // Workspace: h1[128] | MS[2] | pad | mb[nblk] | sb[nblk]  (~27 KB total)
    float* ws  = (float*)d_ws;
    float* h1  = ws;                           // 128
    float* MS  = ws + 128;                     // 2
    const int nal = (nblk + 255) & ~255;
    float* mbp = ws + 256;                     // nblk (aligned)
    float* sbp = mbp + nal;                    // nblk
    (void)n_in; (void)out_size; (void)ws_size;

    k_prep<<<1, 256, 0, stream>>>(hist, W1, b1, h1);
    // raw scores land directly in d_out; normalized in-place afterwards
    k_main<<<nblk, NTHR, 0, stream>>>(action_ids, emb, Qg, W1, W2, b2, h1,
                                      out, mbp, sbp, A);
    k_combine<<<1, 256, 0, stream>>>(mbp, sbp, nblk, MS);
    k_norm<<<(A + 255) / 256, 256, 0, stream>>>(out, MS, out, A);
}

// Round 3
// 388.909 us; speedup vs baseline: 1.3205x; 1.3205x over previous
//
#include <hip/hip_runtime.h>
#include <math.h>

// ---------------------------------------------------------------------------
// PolicyNet scoring, bf16-MFMA version (round 3).
//   rel = emb[action_ids]                          [A,128] gather
//   att = softmax_l(REL @ Q^T)                     [A,64]   (MFMA G1)
//   question = P @ Q                               [A,128]  (MFMA G2)
//   hidden = relu(h1 + question @ W1q^T)           [A,128]  (MFMA G3, chunked)
//   out = hidden @ W2^T + b2                       [A,128]  (MFMA G4, chunked)
//   scores = sum(rel*out,-1); softmax over A
// BA=64 actions/block, 4 waves, wave w owns actions 16w..16w+15 (one M-tile).
// mfma_f32_16x16x32_bf16 fragment maps (guide §3, m89-verified):
//   A: row=lane&15, k=8*(lane>>4)+j (contiguous)   B: col=lane&15, same k
//   C/D: col=lane&15, row=4*(lane>>4)+reg
// All operands stored [row][K] K-contiguous bf16 in LDS, rows padded so b128
// fragment reads are 2-way (free) bank aliased.
// ---------------------------------------------------------------------------

#define BA   64
#define NTHR 256

typedef float          f32x4  __attribute__((ext_vector_type(4)));
typedef short          bf16x8 __attribute__((ext_vector_type(8)));
typedef unsigned short us4v   __attribute__((ext_vector_type(4)));

// LDS arena (ushort units). Regions (all 16B-aligned):
//  RELo: RELbf  [64][136]                    (live whole kernel)
//  R1o : Qbf    [64][136] -> QUESTbf [64][136]
//  R2o : Qt     [128][72] -> HIDbf   [64][136]
//  R3o : Pbf    [64][72]  -> Wchunk  [32][136]
#define RELo 0
#define R1o  8704
#define R2o  17408
#define R3o  26624
#define NB   31232      // 62464 B

__device__ __forceinline__ unsigned short f2bf(float f) {   // RNE, finite in
    unsigned int u = __float_as_uint(f);
    return (unsigned short)((u + 0x7fffu + ((u >> 16) & 1u)) >> 16);
}
__device__ __forceinline__ float bf2f(unsigned short h) {
    return __uint_as_float(((unsigned int)h) << 16);
}

// h1[j] = b1[j] + sum_{k<128} W1[j][k] * hist[k]
__global__ void k_prep(const float* __restrict__ hist, const float* __restrict__ W1,
                       const float* __restrict__ b1, float* __restrict__ h1)
{
    const int lane = threadIdx.x & 63;
    const int w    = threadIdx.x >> 6;
    const float h0  = hist[lane];
    const float h64 = hist[64 + lane];
    #pragma unroll 4
    for (int r = 0; r < 32; ++r) {
        const int j = w * 32 + r;
        float p = fmaf(W1[j * 256 + lane], h0, W1[j * 256 + 64 + lane] * h64);
        #pragma unroll
        for (int o = 1; o < 64; o <<= 1) p += __shfl_xor(p, o);
        if (lane == 0) h1[j] = b1[j] + p;
    }
}

__global__ void __launch_bounds__(NTHR, 2)
k_main(const int* __restrict__ action_ids,
       const float* __restrict__ emb,
       const float* __restrict__ Qg,
       const float* __restrict__ W1,
       const float* __restrict__ W2,
       const float* __restrict__ b2,
       const float* __restrict__ h1g,
       float* __restrict__ scores,
       float* __restrict__ mb,
       float* __restrict__ sb,
       int A)
{
    __shared__ __align__(16) unsigned short B_[NB];
    __shared__ float h1s[128];
    __shared__ float b2s[128];
    __shared__ float stash[BA];

    const int tid  = threadIdx.x;
    const int a0   = blockIdx.x * BA;
    const int w    = tid >> 6;          // wave id: owns actions 16w..16w+15
    const int lane = tid & 63;
    const int c    = lane & 15;         // frag col / A-row select
    const int g    = lane >> 4;         // frag k-block / D row-group

    // ---- P0: stage Qbf [64][136], Qt [128][72], RELbf [64][136], h1, b2 ----
    {
        const int l = tid >> 2, seg = tid & 3;       // 4 threads per row
        const float4* qs = (const float4*)&Qg[l * 128 + seg * 32];
        unsigned short qb[32];
        #pragma unroll
        for (int j = 0; j < 8; ++j) {
            const float4 v = qs[j];
            qb[j*4+0] = f2bf(v.x); qb[j*4+1] = f2bf(v.y);
            qb[j*4+2] = f2bf(v.z); qb[j*4+3] = f2bf(v.w);
            us4v p = { qb[j*4+0], qb[j*4+1], qb[j*4+2], qb[j*4+3] };
            *(us4v*)&B_[R1o + l * 136 + seg * 32 + j * 4] = p;
        }
        #pragma unroll
        for (int i = 0; i < 32; ++i)                 // transposed copy for G2
            B_[R2o + (seg * 32 + i) * 72 + l] = qb[i];

        const int ga  = a0 + l;
        const int rid = (ga < A) ? action_ids[ga] : 0;
        const float4* es = (const float4*)&emb[(size_t)rid * 128 + seg * 32];
        #pragma unroll
        for (int j = 0; j < 8; ++j) {
            const float4 v = es[j];
            us4v p = { f2bf(v.x), f2bf(v.y), f2bf(v.z), f2bf(v.w) };
            *(us4v*)&B_[RELo + l * 136 + seg * 32 + j * 4] = p;
        }
        if (tid < 128) h1s[tid] = h1g[tid];
        else           b2s[tid - 128] = b2[tid - 128];
    }
    __syncthreads();

    // ---- G1: ATT[16w..][64] = REL @ Q^T (K=128), 4 n-tiles, 4 k-steps ----
    f32x4 att[4] = {};
    #pragma unroll
    for (int ks = 0; ks < 4; ++ks) {
        const bf16x8 afr = *(const bf16x8*)&B_[RELo + (16*w + c)*136 + ks*32 + g*8];
        #pragma unroll
        for (int nt = 0; nt < 4; ++nt) {
            const bf16x8 bfr = *(const bf16x8*)&B_[R1o + (16*nt + c)*136 + ks*32 + g*8];
            att[nt] = __builtin_amdgcn_mfma_f32_16x16x32_bf16(afr, bfr, att[nt], 0, 0, 0);
        }
    }

    // ---- softmax over l per action row; P -> R3 bf16 [64][72] ----
    // lane holds rows a=16w+4g+r (r=0..3), cols l=16nt+c.
    {
        float m[4] = { -INFINITY, -INFINITY, -INFINITY, -INFINITY };
        #pragma unroll
        for (int nt = 0; nt < 4; ++nt)
            #pragma unroll
            for (int r = 0; r < 4; ++r) m[r] = fmaxf(m[r], att[nt][r]);
        #pragma unroll
        for (int r = 0; r < 4; ++r) {
            m[r] = fmaxf(m[r], __shfl_xor(m[r], 1));
            m[r] = fmaxf(m[r], __shfl_xor(m[r], 2));
            m[r] = fmaxf(m[r], __shfl_xor(m[r], 4));
            m[r] = fmaxf(m[r], __shfl_xor(m[r], 8));
        }
        float s[4] = { 0.f, 0.f, 0.f, 0.f };
        #pragma unroll
        for (int nt = 0; nt < 4; ++nt)
            #pragma unroll
            for (int r = 0; r < 4; ++r) {
                att[nt][r] = __expf(att[nt][r] - m[r]);
                s[r] += att[nt][r];
            }
        #pragma unroll
        for (int r = 0; r < 4; ++r) {
            s[r] += __shfl_xor(s[r], 1);
            s[r] += __shfl_xor(s[r], 2);
            s[r] += __shfl_xor(s[r], 4);
            s[r] += __shfl_xor(s[r], 8);
            s[r] = 1.f / s[r];
        }
        #pragma unroll
        for (int nt = 0; nt < 4; ++nt)
            #pragma unroll
            for (int r = 0; r < 4; ++r)
                B_[R3o + (16*w + 4*g + r)*72 + 16*nt + c] =
                    f2bf(att[nt][r] * s[r]);
    }
    // own-wave P rows are read only by this wave; Qt stable -> no barrier yet

    // ---- G2: QUEST[16w..][128] = P @ Q (K=64), 8 n-tiles, 2 k-steps ----
    f32x4 qacc[8] = {};
    #pragma unroll
    for (int ks = 0; ks < 2; ++ks) {
        const bf16x8 afr = *(const bf16x8*)&B_[R3o + (16*w + c)*72 + ks*32 + g*8];
        #pragma unroll
        for (int nt = 0; nt < 8; ++nt) {
            const bf16x8 bfr = *(const bf16x8*)&B_[R2o + (16*nt + c)*72 + ks*32 + g*8];
            qacc[nt] = __builtin_amdgcn_mfma_f32_16x16x32_bf16(afr, bfr, qacc[nt], 0, 0, 0);
        }
    }
    __syncthreads();   // all waves done reading Qbf(R1)/P(R3)/Qt(R2)

    // QUEST -> R1 (over Qbf), bf16 [64][136]
    #pragma unroll
    for (int nt = 0; nt < 8; ++nt)
        #pragma unroll
        for (int r = 0; r < 4; ++r)
            B_[R1o + (16*w + 4*g + r)*136 + 16*nt + c] = f2bf(qacc[nt][r]);

    // ---- G3: HID = relu(h1 + QUEST @ W1q^T), W1q in 4 chunks of 32 rows ----
    f32x4 hacc[8] = {};
    for (int ch = 0; ch < 4; ++ch) {
        if (ch) __syncthreads();               // prior chunk reads done
        {   // stage Wc[jl][d] = W1[ch*32+jl][128+d], [32][136] bf16
            const int jl = tid >> 3, seg = tid & 7;
            const float4* src = (const float4*)&W1[(ch*32 + jl)*256 + 128 + seg*16];
            #pragma unroll
            for (int j = 0; j < 4; ++j) {
                const float4 v = src[j];
                us4v p = { f2bf(v.x), f2bf(v.y), f2bf(v.z), f2bf(v.w) };
                *(us4v*)&B_[R3o + jl*136 + seg*16 + j*4] = p;
            }
        }
        __syncthreads();
        #pragma unroll
        for (int ks = 0; ks < 4; ++ks) {
            const bf16x8 afr = *(const bf16x8*)&B_[R1o + (16*w + c)*136 + ks*32 + g*8];
            #pragma unroll
            for (int nt = 0; nt < 2; ++nt) {
                const bf16x8 bfr = *(const bf16x8*)&B_[R3o + (16*nt + c)*136 + ks*32 + g*8];
                hacc[ch*2+nt] = __builtin_amdgcn_mfma_f32_16x16x32_bf16(afr, bfr, hacc[ch*2+nt], 0, 0, 0);
            }
        }
    }
    __syncthreads();   // all G3 chunk reads done (R3 free); Qt long dead (R2 free)

    // h1 + relu; HID -> R2, bf16 [64][136]
    #pragma unroll
    for (int ch = 0; ch < 4; ++ch)
        #pragma unroll
        for (int nt = 0; nt < 2; ++nt) {
            const int j = ch*32 + nt*16 + c;
            const float hb = h1s[j];
            #pragma unroll
            for (int r = 0; r < 4; ++r) {
                const float hv = fmaxf(hacc[ch*2+nt][r] + hb, 0.f);
                B_[R2o + (16*w + 4*g + r)*136 + j] = f2bf(hv);
            }
        }

    // ---- G4: OUT = HID @ W2^T + b2 (d-chunks of 32); score = sum(REL*OUT) --
    float sacc[4] = { 0.f, 0.f, 0.f, 0.f };
    for (int ch = 0; ch < 4; ++ch) {
        if (ch) __syncthreads();
        {   // stage Wc[dl][j] = W2[ch*32+dl][j], [32][136] bf16
            const int dl = tid >> 3, seg = tid & 7;
            const float4* src = (const float4*)&W2[(ch*32 + dl)*128 + seg*16];
            #pragma unroll
            for (int j = 0; j < 4; ++j) {
                const float4 v = src[j];
                us4v p = { f2bf(v.x), f2bf(v.y), f2bf(v.z), f2bf(v.w) };
                *(us4v*)&B_[R3o + dl*136 + seg*16 + j*4] = p;
            }
        }
        __syncthreads();
        f32x4 oacc[2] = {};
        #pragma unroll
        for (int ks = 0; ks < 4; ++ks) {
            const bf16x8 afr = *(const bf16x8*)&B_[R2o + (16*w + c)*136 + ks*32 + g*8];
            #pragma unroll
            for (int nt = 0; nt < 2; ++nt) {
                const bf16x8 bfr = *(const bf16x8*)&B_[R3o + (16*nt + c)*136 + ks*32 + g*8];
                oacc[nt] = __builtin_amdgcn_mfma_f32_16x16x32_bf16(afr, bfr, oacc[nt], 0, 0, 0);
            }
        }
        #pragma unroll
        for (int nt = 0; nt < 2; ++nt) {
            const int d = ch*32 + nt*16 + c;
            const float bb = b2s[d];
            #pragma unroll
            for (int r = 0; r < 4; ++r) {
                const float ov = oacc[nt][r] + bb;
                const float rv = bf2f(B_[RELo + (16*w + 4*g + r)*136 + d]);
                sacc[r] = fmaf(ov, rv, sacc[r]);
            }
        }
    }

    // reduce score over cols (lane bits 0..3); write scores + stash
    #pragma unroll
    for (int r = 0; r < 4; ++r) {
        sacc[r] += __shfl_xor(sacc[r], 1);
        sacc[r] += __shfl_xor(sacc[r], 2);
        sacc[r] += __shfl_xor(sacc[r], 4);
        sacc[r] += __shfl_xor(sacc[r], 8);
    }
    if (c == 0) {
        #pragma unroll
        for (int r = 0; r < 4; ++r) {
            const int al = 16*w + 4*g + r;
            const int ga = a0 + al;
            if (ga < A) scores[ga] = sacc[r];
            stash[al] = sacc[r];
        }
    }
    __syncthreads();

    // ---- per-block softmax partials over the 64 tile scores ----
    if (tid < 64) {
        const bool valid = (a0 + tid) < A;
        float sv = valid ? stash[tid] : -INFINITY;
        float m = sv;
        #pragma unroll
        for (int o = 1; o < 64; o <<= 1) m = fmaxf(m, __shfl_xor(m, o));
        float ex = valid ? __expf(sv - m) : 0.f;
        #pragma unroll
        for (int o = 1; o < 64; o <<= 1) ex += __shfl_xor(ex, o);
        if (tid == 0) { mb[blockIdx.x] = m; sb[blockIdx.x] = ex; }
    }
}

// Combine per-block (m, s) partials into global M and 1/S.
__global__ void k_combine(const float* __restrict__ mb, const float* __restrict__ sb,
                          int n, float* __restrict__ MS)
{
    __shared__ float red[256];
    const int tid = threadIdx.x;
    float m = -INFINITY;
    for (int i = tid; i < n; i += 256) m = fmaxf(m, mb[i]);
    red[tid] = m; __syncthreads();
    for (int s = 128; s > 0; s >>= 1) {
        if (tid < s) red[tid] = fmaxf(red[tid], red[tid + s]);
        __syncthreads();
    }
    const float M = red[0];
    __syncthreads();
    float sum = 0.f;
    for (int i = tid; i < n; i += 256) sum += sb[i] * __expf(mb[i] - M);
    red[tid] = sum; __syncthreads();
    for (int s = 128; s > 0; s >>= 1) {
        if (tid < s) red[tid] += red[tid + s];
        __syncthreads();
    }
    if (tid == 0) { MS[0] = M; MS[1] = 1.f / red[0]; }
}

// In-place: d_out holds raw scores; replace with softmax.
__global__ void k_norm(const float* __restrict__ scores, const float* __restrict__ MS,
                       float* __restrict__ out, int A)
{
    const int i = blockIdx.x * blockDim.x + threadIdx.x;
    if (i < A) out[i] = __expf(scores[i] - MS[0]) * MS[1];
}

extern "C" void kernel_launch(void* const* d_in, const int* in_sizes, int n_in,
                              void* d_out, int out_size, void* d_ws, size_t ws_size,
                              hipStream_t stream)
{
    const int*   action_ids = (const int*)  d_in[0];
    const float* emb        = (const float*)d_in[1];
    const float* Qg         = (const float*)d_in[2];
    const float* hist       = (const float*)d_in[3];
    const float* W1         = (const float*)d_in[4];
    const float* b1         = (const float*)d_in[5];
    const float* W2         = (const float*)d_in[6];
    const float* b2         = (const float*)d_in[7];
    float* out = (float*)d_out;
    const int A    = in_sizes[0];
    const int nblk = (A + BA - 1) / BA;

    // Workspace: h1[128] | MS[2] | pad | mb[nblk] | sb[nblk]  (~16 KB)
    float* ws  = (float*)d_ws;
    float* h1  = ws;                           // 128
    float* MS  = ws + 128;                     // 2
    const int nal = (nblk + 255) & ~255;
    float* mbp = ws + 256;                     // nblk (aligned)
    float* sbp = mbp + nal;                    // nblk
    (void)n_in; (void)out_size; (void)ws_size;

    k_prep<<<1, 256, 0, stream>>>(hist, W1, b1, h1);
    // raw scores land directly in d_out; normalized in-place afterwards
    k_main<<<nblk, NTHR, 0, stream>>>(action_ids, emb, Qg, W1, W2, b2, h1,
                                      out, mbp, sbp, A);
    k_combine<<<1, 256, 0, stream>>>(mbp, sbp, nblk, MS);
    k_norm<<<(A + 255) / 256, 256, 0, stream>>>(out, MS, out, A);
}